// Round 6
// baseline (2081.554 us; speedup 1.0000x reference)
//
#include <hip/hip_runtime.h>

typedef __bf16 bf16_t;

#define T_SEQ 1536
#define LDQKV 5120
#define SM_SCALE 0.125f

// ---------- naive tiled GEMM: C(M,N) = A(M,K) @ B(K,N) + bias ----------
// A is fp32 or bf16 (a_bf16 flag); B/bias always fp32; C fp32 or bf16.
// 64x64 tile, 256 threads, 4x4 outputs/thread, K-tile 32.
__global__ __launch_bounds__(256)
void gemm_naive(const void* __restrict__ A, const float* __restrict__ B,
                const float* __restrict__ bias, void* __restrict__ C,
                int M, int N, int K, int a_bf16, int out_bf16) {
  __shared__ float As[64 * 33];
  __shared__ float Bs[32 * 65];
  const int tid = threadIdx.x;
  const int m0 = blockIdx.y * 64, n0 = blockIdx.x * 64;
  const int ty = tid >> 4, tx = tid & 15;
  const int ar = tid >> 2, ak = (tid & 3) * 8;   // A staging: row 0..63, k base
  const int bk = tid >> 3, bn = (tid & 7) * 8;   // B staging: k row 0..31, n base
  float acc[4][4] = {};

  for (int k0 = 0; k0 < K; k0 += 32) {
    __syncthreads();
    if (a_bf16) {
      const bf16_t* Ab = (const bf16_t*)A;
#pragma unroll
      for (int e = 0; e < 8; ++e)
        As[ar * 33 + ak + e] = (float)Ab[(size_t)(m0 + ar) * K + k0 + ak + e];
    } else {
      const float* Af = (const float*)A;
#pragma unroll
      for (int e = 0; e < 8; ++e)
        As[ar * 33 + ak + e] = Af[(size_t)(m0 + ar) * K + k0 + ak + e];
    }
#pragma unroll
    for (int e = 0; e < 8; ++e)
      Bs[bk * 65 + bn + e] = B[(size_t)(k0 + bk) * N + n0 + bn + e];
    __syncthreads();
#pragma unroll 4
    for (int k = 0; k < 32; ++k) {
      float av[4], bv[4];
#pragma unroll
      for (int i = 0; i < 4; ++i) av[i] = As[(ty * 4 + i) * 33 + k];
#pragma unroll
      for (int j = 0; j < 4; ++j) bv[j] = Bs[k * 65 + tx * 4 + j];
#pragma unroll
      for (int i = 0; i < 4; ++i)
#pragma unroll
        for (int j = 0; j < 4; ++j)
          acc[i][j] += av[i] * bv[j];
    }
  }
#pragma unroll
  for (int i = 0; i < 4; ++i) {
    int m = m0 + ty * 4 + i;
#pragma unroll
    for (int j = 0; j < 4; ++j) {
      int n = n0 + tx * 4 + j;
      float v = acc[i][j] + bias[n];
      if (out_bf16) ((bf16_t*)C)[(size_t)m * N + n] = (bf16_t)v;
      else          ((float*)C)[(size_t)m * N + n] = v;
    }
  }
}

// ---------- RoPE (YaRN) on q (cols 0..4095) and k (4096..4607), bf16 qkv ----
__global__ __launch_bounds__(256)
void rope_kernel(bf16_t* __restrict__ qkv) {
  int idx = blockIdx.x * 256 + threadIdx.x;   // 1536*72*32 threads
  int d = idx & 31;
  int rest = idx >> 5;
  int u = rest % 72;
  int t = rest / 72;
  if (t >= T_SEQ) return;
  int col = (u < 64) ? (u * 64) : (4096 + (u - 64) * 64);
  size_t off = (size_t)t * LDQKV + col + d;
  float x1 = (float)qkv[off];
  float x2 = (float)qkv[off + 32];
  const float lowv = 4.370846f;     // 32*ln(1024/(32*2pi))/ln(150000)
  const float highv = 13.675927f;   // 32*ln(1024/(2pi))/ln(150000)
  const float conc = 1.3465736f;    // 0.1*ln(32)+1
  float ramp = ((float)d - lowv) / (highv - lowv);
  ramp = fminf(fmaxf(ramp, 0.f), 1.f);
  float freq = exp2f((float)d * 0.53733134f);  // 150000^(d/32)
  float inv_freq = ramp / (32.f * freq) + (1.f - ramp) / freq;
  float ang = (float)t * inv_freq;
  float c = cosf(ang) * conc;
  float s = sinf(ang) * conc;
  qkv[off]      = (bf16_t)(x1 * c - x2 * s);
  qkv[off + 32] = (bf16_t)(x2 * c + x1 * s);
}

// ---------- naive sliding-window GQA attention with sink ----------
// grid (i=1536, kvh=8); block 256. LDS-staged K/V window, serial softmax.
__global__ __launch_bounds__(256)
void attn_naive(const bf16_t* __restrict__ qkv, const float* __restrict__ sinks,
                bf16_t* __restrict__ attno) {
  __shared__ bf16_t Ks[128 * 66];
  __shared__ bf16_t Vs[128 * 66];
  __shared__ bf16_t Qs[8 * 64];
  __shared__ float Sc[8][128];
  __shared__ float inv[8];
  const int i = blockIdx.x, kvh = blockIdx.y;
  const int tid = threadIdx.x;
  const int j0 = (i >= 127) ? (i - 127) : 0;
  const int W = i - j0 + 1;

  for (int idx = tid; idx < W * 64; idx += 256) {
    int jr = idx >> 6, d = idx & 63;
    size_t row = (size_t)(j0 + jr) * LDQKV;
    Ks[jr * 66 + d] = qkv[row + 4096 + kvh * 64 + d];
    Vs[jr * 66 + d] = qkv[row + 4608 + kvh * 64 + d];
  }
  for (int idx = tid; idx < 512; idx += 256)
    Qs[idx] = qkv[(size_t)i * LDQKV + kvh * 512 + idx];
  __syncthreads();

  // scores: 8 heads x W keys
  for (int it = tid; it < 8 * 128; it += 256) {
    int h = it >> 7, t = it & 127;
    if (t < W) {
      float s = 0.f;
      for (int d = 0; d < 64; ++d)
        s += (float)Qs[h * 64 + d] * (float)Ks[t * 66 + d];
      Sc[h][t] = s * SM_SCALE;
    }
  }
  __syncthreads();
  // softmax (serial per head, 8 heads in parallel)
  if (tid < 8) {
    int h = tid;
    float m = -1e30f;
    for (int t = 0; t < W; ++t) m = fmaxf(m, Sc[h][t]);
    float l = 0.f;
    for (int t = 0; t < W; ++t) { float p = __expf(Sc[h][t] - m); Sc[h][t] = p; l += p; }
    inv[h] = 1.f / (l + __expf(sinks[kvh * 8 + h] - m));
  }
  __syncthreads();
  // O = P @ V
  for (int it = tid; it < 512; it += 256) {
    int h = it >> 6, d = it & 63;
    float o = 0.f;
    for (int t = 0; t < W; ++t) o += Sc[h][t] * (float)Vs[t * 66 + d];
    attno[(size_t)i * 4096 + kvh * 512 + it] = (bf16_t)(o * inv[h]);
  }
}

// ---------- diagnostic sentinel: ws too small ----------
__global__ __launch_bounds__(256)
void sentinel_fill(float* __restrict__ out, int n) {
  int i = blockIdx.x * 256 + threadIdx.x;
  if (i < n) out[i] = 10000.0f;
}

extern "C" void kernel_launch(void* const* d_in, const int* in_sizes, int n_in,
                              void* d_out, int out_size, void* d_ws, size_t ws_size,
                              hipStream_t stream) {
  // identify inputs by flat element count (all distinct); dtypes per reference: fp32
  const float *x = nullptr, *Wqkv = nullptr, *bqkv = nullptr,
              *Wout = nullptr, *bout = nullptr, *sinks = nullptr;
  for (int i = 0; i < n_in; ++i) {
    switch (in_sizes[i]) {
      case 1536 * 2880:  x = (const float*)d_in[i]; break;
      case 2880 * 5120:  Wqkv = (const float*)d_in[i]; break;
      case 5120:         bqkv = (const float*)d_in[i]; break;
      case 4096 * 2880:  Wout = (const float*)d_in[i]; break;
      case 2880:         bout = (const float*)d_in[i]; break;
      case 64:           sinks = (const float*)d_in[i]; break;
      default: break;
    }
  }

  const size_t REQ = ((size_t)1536 * 5120 + (size_t)1536 * 4096) * sizeof(bf16_t);
  if (ws_size < REQ || !x || !Wqkv || !bqkv || !Wout || !bout || !sinks) {
    sentinel_fill<<<(out_size + 255) / 256, 256, 0, stream>>>((float*)d_out, out_size);
    return;
  }

  bf16_t* qkv   = (bf16_t*)d_ws;                   // 1536*5120 bf16 (15.7 MB)
  bf16_t* attno = qkv + (size_t)1536 * 5120;       // 1536*4096 bf16 (12.6 MB)

  gemm_naive<<<dim3(5120 / 64, 1536 / 64), 256, 0, stream>>>(
      x, Wqkv, bqkv, qkv, 1536, 5120, 2880, /*a_bf16=*/0, /*out_bf16=*/1);
  rope_kernel<<<dim3((1536 * 72 * 32) / 256), 256, 0, stream>>>(qkv);
  attn_naive<<<dim3(1536, 8), 256, 0, stream>>>(qkv, sinks, attno);
  gemm_naive<<<dim3(2880 / 64, 1536 / 64), 256, 0, stream>>>(
      attno, Wout, bout, d_out, 1536, 2880, 4096, /*a_bf16=*/1, /*out_bf16=*/0);
}

// Round 7
// 632.768 us; speedup vs baseline: 3.2896x; 3.2896x over previous
//
#include <hip/hip_runtime.h>

typedef __bf16 bf16_t;
typedef __bf16 bfrag8 __attribute__((ext_vector_type(8)));
typedef float f32x4 __attribute__((ext_vector_type(4)));

#define T_SEQ 1536
#define LDQKV 5120
#define SM_SCALE 0.125f

__device__ __forceinline__ unsigned short b2u(bf16_t h) {
  union { bf16_t h; unsigned short u; } c; c.h = h; return c.u;
}
__device__ __forceinline__ unsigned int pack2(float lo, float hi) {
  return (unsigned int)b2u((bf16_t)lo) | ((unsigned int)b2u((bf16_t)hi) << 16);
}

// ------- MFMA GEMM: C(M,N) = A(M,K) @ B(K,N) + bias.
// A: fp32 (a_bf16=0) or bf16 (a_bf16=1); B,bias: fp32; C: bf16 (out_bf16=1) or fp32.
// 128x128 tile, 4 waves, 4x4 16x16x32 bf16 MFMA per wave, BK=64.
__global__ __launch_bounds__(256, 2)
void gemm_mfma(const void* __restrict__ A, const float* __restrict__ B,
               const float* __restrict__ bias, void* __restrict__ C,
               int M, int N, int K, int a_bf16, int out_bf16) {
  __shared__ __align__(16) bf16_t As[128 * 64];   // [m][k] stride 64 (128 B)
  __shared__ __align__(16) bf16_t Bs[128 * 72];   // [n][k] stride 72 (144 B)
  const int tid = threadIdx.x;
  const int wave = tid >> 6;
  const int lane = tid & 63;
  const int g = lane >> 4;     // 0..3
  const int lm = lane & 15;    // 0..15
  const int m0 = blockIdx.y * 128;
  const int n0 = blockIdx.x * 128;
  const int wm = (wave >> 1) * 64;
  const int wn = (wave & 1) * 64;
  const int sr = lane >> 3;    // 0..7 row within 8-row chunk (A staging)
  const int seg = lane & 7;    // 0..7 16B segment (A staging)
  const int pairk = tid & 31;  // k-pair 0..31 (B staging)
  const int cg = tid >> 5;     // 0..7 col-group of 16 (B staging)

  int cb = n0 + cg * 16;
  if (cb > N - 16) cb = N - 16;   // clamp ragged N (N multiple of 16)

  const f32x4 fz = {0.f, 0.f, 0.f, 0.f};
  f32x4 acc[4][4];
#pragma unroll
  for (int i = 0; i < 4; ++i)
#pragma unroll
    for (int j = 0; j < 4; ++j) acc[i][j] = fz;

  for (int k0 = 0; k0 < K; k0 += 64) {
    // ---- load tiles to registers ----
    bfrag8 areg[4];
    if (a_bf16) {
#pragma unroll
      for (int it = 0; it < 4; ++it) {
        int ra = (wave * 4 + it) * 8 + sr;
        areg[it] = *(const bfrag8*)((const bf16_t*)A + (size_t)(m0 + ra) * K + k0 + seg * 8);
      }
    } else {
#pragma unroll
      for (int it = 0; it < 4; ++it) {
        int ra = (wave * 4 + it) * 8 + sr;
        const float* ga = (const float*)A + (size_t)(m0 + ra) * K + k0 + seg * 8;
        f32x4 a0 = *(const f32x4*)ga;
        f32x4 a1 = *(const f32x4*)(ga + 4);
#pragma unroll
        for (int e = 0; e < 4; ++e) {
          areg[it][e]     = (bf16_t)a0[e];
          areg[it][e + 4] = (bf16_t)a1[e];
        }
      }
    }
    int kk = 2 * pairk;
    unsigned int pk[16];
    {
      const float* b0 = B + (size_t)(k0 + kk) * N + cb;
      const float* b1 = B + (size_t)(k0 + kk + 1) * N + cb;
      f32x4 x0 = *(const f32x4*)(b0),     x1 = *(const f32x4*)(b0 + 4);
      f32x4 x2 = *(const f32x4*)(b0 + 8), x3 = *(const f32x4*)(b0 + 12);
      f32x4 y0 = *(const f32x4*)(b1),     y1 = *(const f32x4*)(b1 + 4);
      f32x4 y2 = *(const f32x4*)(b1 + 8), y3 = *(const f32x4*)(b1 + 12);
#pragma unroll
      for (int e = 0; e < 4; ++e) {
        pk[e]      = pack2(x0[e], y0[e]);
        pk[e + 4]  = pack2(x1[e], y1[e]);
        pk[e + 8]  = pack2(x2[e], y2[e]);
        pk[e + 12] = pack2(x3[e], y3[e]);
      }
    }

    __syncthreads();
#pragma unroll
    for (int it = 0; it < 4; ++it) {
      int ra = (wave * 4 + it) * 8 + sr;
      *(bfrag8*)(As + ra * 64 + seg * 8) = areg[it];
    }
#pragma unroll
    for (int n = 0; n < 16; ++n)
      *(unsigned int*)(Bs + (cg * 16 + n) * 72 + kk) = pk[n];
    __syncthreads();
    // ---- MFMA inner loop ----
#pragma unroll
    for (int ks = 0; ks < 2; ++ks) {
      bfrag8 af[4], bfr[4];
#pragma unroll
      for (int i = 0; i < 4; ++i) {
        af[i]  = *(const bfrag8*)(As + (wm + i * 16 + lm) * 64 + ks * 32 + g * 8);
        bfr[i] = *(const bfrag8*)(Bs + (wn + i * 16 + lm) * 72 + ks * 32 + g * 8);
      }
#pragma unroll
      for (int i = 0; i < 4; ++i)
#pragma unroll
        for (int j = 0; j < 4; ++j)
          acc[i][j] = __builtin_amdgcn_mfma_f32_16x16x32_bf16(af[i], bfr[j],
                                                              acc[i][j], 0, 0, 0);
    }
  }
  // epilogue: C/D layout col(n) = lane&15, row(m) = (lane>>4)*4 + reg
#pragma unroll
  for (int j = 0; j < 4; ++j) {
    int n = n0 + wn + j * 16 + lm;
    if (n >= N) continue;
    float bv = bias[n];
#pragma unroll
    for (int i = 0; i < 4; ++i) {
      int mr = m0 + wm + i * 16 + g * 4;
#pragma unroll
      for (int r = 0; r < 4; ++r) {
        float v = acc[i][j][r] + bv;
        size_t off = (size_t)(mr + r) * N + n;
        if (out_bf16) ((bf16_t*)C)[off] = (bf16_t)v;
        else          ((float*)C)[off] = v;
      }
    }
  }
}

// ---------- RoPE (YaRN) on q (cols 0..4095) and k (4096..4607), bf16 qkv ----
__global__ __launch_bounds__(256)
void rope_kernel(bf16_t* __restrict__ qkv) {
  int idx = blockIdx.x * 256 + threadIdx.x;   // 1536*72*32 threads
  int d = idx & 31;
  int rest = idx >> 5;
  int u = rest % 72;
  int t = rest / 72;
  if (t >= T_SEQ) return;
  int col = (u < 64) ? (u * 64) : (4096 + (u - 64) * 64);
  size_t off = (size_t)t * LDQKV + col + d;
  float x1 = (float)qkv[off];
  float x2 = (float)qkv[off + 32];
  const float lowv = 4.370846f;     // 32*ln(1024/(32*2pi))/ln(150000)
  const float highv = 13.675927f;   // 32*ln(1024/(2pi))/ln(150000)
  const float conc = 1.3465736f;    // 0.1*ln(32)+1
  float ramp = ((float)d - lowv) / (highv - lowv);
  ramp = fminf(fmaxf(ramp, 0.f), 1.f);
  float freq = exp2f((float)d * 0.53733134f);  // 150000^(d/32)
  float inv_freq = ramp / (32.f * freq) + (1.f - ramp) / freq;
  float ang = (float)t * inv_freq;
  float c = cosf(ang) * conc;
  float s = sinf(ang) * conc;
  qkv[off]      = (bf16_t)(x1 * c - x2 * s);
  qkv[off + 32] = (bf16_t)(x2 * c + x1 * s);
}

// ---------- naive sliding-window GQA attention with sink (validated) ----------
__global__ __launch_bounds__(256)
void attn_naive(const bf16_t* __restrict__ qkv, const float* __restrict__ sinks,
                bf16_t* __restrict__ attno) {
  __shared__ bf16_t Ks[128 * 66];
  __shared__ bf16_t Vs[128 * 66];
  __shared__ bf16_t Qs[8 * 64];
  __shared__ float Sc[8][128];
  __shared__ float inv[8];
  const int i = blockIdx.x, kvh = blockIdx.y;
  const int tid = threadIdx.x;
  const int j0 = (i >= 127) ? (i - 127) : 0;
  const int W = i - j0 + 1;

  for (int idx = tid; idx < W * 64; idx += 256) {
    int jr = idx >> 6, d = idx & 63;
    size_t row = (size_t)(j0 + jr) * LDQKV;
    Ks[jr * 66 + d] = qkv[row + 4096 + kvh * 64 + d];
    Vs[jr * 66 + d] = qkv[row + 4608 + kvh * 64 + d];
  }
  for (int idx = tid; idx < 512; idx += 256)
    Qs[idx] = qkv[(size_t)i * LDQKV + kvh * 512 + idx];
  __syncthreads();

  for (int it = tid; it < 8 * 128; it += 256) {
    int h = it >> 7, t = it & 127;
    if (t < W) {
      float s = 0.f;
      for (int d = 0; d < 64; ++d)
        s += (float)Qs[h * 64 + d] * (float)Ks[t * 66 + d];
      Sc[h][t] = s * SM_SCALE;
    }
  }
  __syncthreads();
  if (tid < 8) {
    int h = tid;
    float m = -1e30f;
    for (int t = 0; t < W; ++t) m = fmaxf(m, Sc[h][t]);
    float l = 0.f;
    for (int t = 0; t < W; ++t) { float p = __expf(Sc[h][t] - m); Sc[h][t] = p; l += p; }
    inv[h] = 1.f / (l + __expf(sinks[kvh * 8 + h] - m));
  }
  __syncthreads();
  for (int it = tid; it < 512; it += 256) {
    int h = it >> 6, d = it & 63;
    float o = 0.f;
    for (int t = 0; t < W; ++t) o += Sc[h][t] * (float)Vs[t * 66 + d];
    attno[(size_t)i * 4096 + kvh * 512 + it] = (bf16_t)(o * inv[h]);
  }
}

// ---------- diagnostic sentinel: ws too small ----------
__global__ __launch_bounds__(256)
void sentinel_fill(float* __restrict__ out, int n) {
  int i = blockIdx.x * 256 + threadIdx.x;
  if (i < n) out[i] = 10000.0f;
}

extern "C" void kernel_launch(void* const* d_in, const int* in_sizes, int n_in,
                              void* d_out, int out_size, void* d_ws, size_t ws_size,
                              hipStream_t stream) {
  const float *x = nullptr, *Wqkv = nullptr, *bqkv = nullptr,
              *Wout = nullptr, *bout = nullptr, *sinks = nullptr;
  for (int i = 0; i < n_in; ++i) {
    switch (in_sizes[i]) {
      case 1536 * 2880:  x = (const float*)d_in[i]; break;
      case 2880 * 5120:  Wqkv = (const float*)d_in[i]; break;
      case 5120:         bqkv = (const float*)d_in[i]; break;
      case 4096 * 2880:  Wout = (const float*)d_in[i]; break;
      case 2880:         bout = (const float*)d_in[i]; break;
      case 64:           sinks = (const float*)d_in[i]; break;
      default: break;
    }
  }

  const size_t REQ = ((size_t)1536 * 5120 + (size_t)1536 * 4096) * sizeof(bf16_t);
  if (ws_size < REQ || !x || !Wqkv || !bqkv || !Wout || !bout || !sinks) {
    sentinel_fill<<<(out_size + 255) / 256, 256, 0, stream>>>((float*)d_out, out_size);
    return;
  }

  bf16_t* qkv   = (bf16_t*)d_ws;                   // 1536*5120 bf16 (15.7 MB)
  bf16_t* attno = qkv + (size_t)1536 * 5120;       // 1536*4096 bf16 (12.6 MB)

  gemm_mfma<<<dim3(5120 / 128, 1536 / 128), 256, 0, stream>>>(
      x, Wqkv, bqkv, qkv, 1536, 5120, 2880, /*a_bf16=*/0, /*out_bf16=*/1);
  rope_kernel<<<dim3((1536 * 72 * 32) / 256), 256, 0, stream>>>(qkv);
  attn_naive<<<dim3(1536, 8), 256, 0, stream>>>(qkv, sinks, attno);
  gemm_mfma<<<dim3((2880 + 127) / 128, 1536 / 128), 256, 0, stream>>>(
      attno, Wout, bout, d_out, 1536, 2880, 4096, /*a_bf16=*/1, /*out_bf16=*/0);
}